// Round 10
// baseline (832.274 us; speedup 1.0000x reference)
//
#include <hip/hip_runtime.h>
#include <cfloat>

// ClDiceLoss (B=2, C=1, 192^3) fp32 — LDS-staged register-streaming skeletonize.
//
// Round-17 = the r15 occupancy experiment, de-risked after two container
// failures (audit: no OOB, no barrier divergence, no waitcnt deadlock —
// s_waitcnt drains monotonically, barriers uniform at 17/wave; staging
// mechanism byte-identical in structure to r7 which passed absmax=0).
// De-risk delta vs r16: dummy-store dump shrunk from MAXWG*192 floats to
// ONE shared 768B row (racy garbage writes, never read, harmless) so
// need_merged (226.7MB) is strictly below the workspace floor r7 proved
// (227.8MB) — removes the only untested branch.
//
// Design: raise residency ceiling AND supply together:
//   - slab ring 3 (18.4KB): LDS cap 8 blocks/CU.
//   - CZ=12 (NCH=16): 3072 blocks = 12/CU supplied.
//   - 1-ahead unsinkable staging (global_load_lds), ONE barrier/step.
//     Slot safety: stage(s) targets the slot read at s-2; those reads
//     drained (lgkm inside waitcnt before barrier) before barrier(s-1);
//     stage(s) issues after barrier(s-1). vmcnt retires stage(s-1):
//     4 (last) / 3 (non-last) — induction incl. prologue verified.
// Discriminating test: occupancy ~31% and dur ~74 persisting => residency
// capped outside LDS/VGPR/supply -> pivot to per-wave inline-asm prefetch.
// Kept: bijective XCD swizzle, uniform op protocol (dummy store/weight),
// dwordx3 stores, separable 3x3 max, y/z boundary handling (clamp-dup is
// min-neutral).

constexpr int D = 192, H = 192, W = 192, B = 2;
constexpr int HW = H * W;
constexpr int VOL = D * HW;
constexpr int CZ = 12;               // z-chunk (divides D; mult of 3 for slots)
constexpr int NCH = D / CZ;          // 16
constexpr int WPB = 4;               // waves (rows) per block
constexpr int NGY = H / WPB;         // 48
constexpr int STEPS = 15;            // s=0..14; emit s in [3, CZ+2]=[3,14]
constexpr int NPART = B * NCH * H;   // 6144 per chain
constexpr int DUMPSZ = 192;          // one shared dummy row (racy, write-only)

struct F3 { float x, y, z; };

typedef __attribute__((address_space(3))) float lds_f;
typedef __attribute__((address_space(1))) const float glb_f;

__device__ __forceinline__ float min3f(float a, float b, float c) {
  return fminf(fminf(a, b), c);
}
__device__ __forceinline__ float max3f(float a, float b, float c) {
  return fmaxf(fmaxf(a, b), c);
}

__global__ __launch_bounds__(256, 6) void skel_iter(
    const float* __restrict__ srcA, float* __restrict__ dstA,
    const float* __restrict__ othA, double* __restrict__ partA,
    const float* __restrict__ srcB, float* __restrict__ dstB,
    const float* __restrict__ othB, double* __restrict__ partB,
    float* __restrict__ dump, int last) {
  __shared__ float slab[3][8][192];   // ring-3 of 8-row plane slabs (18.4 KB)

  const int tid = threadIdx.x, lane = tid & 63, wv = tid >> 6;
  const int bid0 = blockIdx.x + gridDim.x * (blockIdx.y + gridDim.y * blockIdx.z);
  const int nwg = gridDim.x * gridDim.y * gridDim.z;
  const int wid = (bid0 & 7) * (nwg >> 3) + (bid0 >> 3);   // XCD swizzle
  const int gyg = wid % NGY;
  const int combo = wid / NGY;
  const int chunk = combo % NCH;
  const int bz = combo / NCH;
  const int b = bz % B;
  const int chain = bz / B;

  const int gy0 = gyg * WPB;
  const int gy = gy0 + wv;

  const float* __restrict__ vs = (chain ? srcB : srcA) + (size_t)b * VOL;
  float* __restrict__ vd = (chain ? dstB : dstA) + (size_t)b * VOL;
  const float* __restrict__ vo = (chain ? othB : othA) + (size_t)b * VOL;
  double* __restrict__ part = chain ? partB : partA;

  const int z0 = chunk * CZ;          // z0 % 3 == 0 (CZ mult of 3)
  const int c0 = 3 * lane;
  const int wrow = gy * W + c0;
  float* __restrict__ dmp = dump + c0;   // shared dummy row; races harmless

  // slab-row read offsets (floats), y-clamped to duplicated edge rows
  int roff[5];
  #pragma unroll
  for (int r = 0; r < 5; ++r) {
    const int i = min(max(gy - 2 + r, 0), H - 1) - (gy0 - 2);
    roff[r] = i * 192 + c0;
  }
  const bool ytop = (gy == 0), ybot = (gy == H - 1);
  const bool l0 = (lane == 0), l63 = (lane == 63);

  // staging rows owned by this wave: slab rows wv and wv+4
  const int g0 = min(max(gy0 - 2 + wv, 0), H - 1);
  const int g1 = min(max(gy0 + 2 + wv, 0), H - 1);

  auto stage = [&](int plane, int slot) {
    const int zc = min(max(plane, 0), D - 1);
    const float* s0 = vs + (size_t)zc * HW + (size_t)g0 * W + c0;
    const float* s1 = vs + (size_t)zc * HW + (size_t)g1 * W + c0;
    __builtin_amdgcn_global_load_lds((glb_f*)s0, (lds_f*)&slab[slot][wv][0], 12, 0, 0);
    __builtin_amdgcn_global_load_lds((glb_f*)s1, (lds_f*)&slab[slot][wv + 4][0], 12, 0, 0);
  };

  float xa[3][5][3];                  // plane reg ring (mod-3)
  float Mprev[3] = {0, 0, 0}, h1[3] = {0, 0, 0}, h2[3] = {0, 0, 0};
  float sp = 0.0f, ss = 0.0f;

  // ---- prologue ----
  // Seed regs: OLD(=xa[1]) <- plane z0-3 rows gy-1..gy+1; MID(=xa[2]) <-
  // plane z0-2 all 5 rows. Then put plane z0-1 in slot 2 (read at s=0).
  stage(z0 - 3, 0);
  stage(z0 - 2, 1);
  asm volatile("s_waitcnt vmcnt(0)" ::: "memory");
  __builtin_amdgcn_s_barrier();
  __builtin_amdgcn_sched_barrier(0);
  {
    const float* sp0 = &slab[0][0][0];
    const float* sp1 = &slab[1][0][0];
    #pragma unroll
    for (int r = 1; r <= 3; ++r) {
      xa[1][r][0] = sp0[roff[r]]; xa[1][r][1] = sp0[roff[r] + 1]; xa[1][r][2] = sp0[roff[r] + 2];
    }
    #pragma unroll
    for (int r = 0; r < 5; ++r) {
      xa[2][r][0] = sp1[roff[r]]; xa[2][r][1] = sp1[roff[r] + 1]; xa[2][r][2] = sp1[roff[r] + 2];
    }
  }
  xa[1][0][0] = xa[1][0][1] = xa[1][0][2] = 0.0f;   // never read; keep defined
  xa[1][4][0] = xa[1][4][1] = xa[1][4][2] = 0.0f;
  stage(z0 - 1, 2);
  *(F3*)dmp = {0.0f, 0.0f, 0.0f};     // protocol store
  asm volatile("s_waitcnt lgkmcnt(0)" ::: "memory");
  __builtin_amdgcn_s_barrier();
  __builtin_amdgcn_sched_barrier(0);

  #pragma unroll 1
  for (int s3 = 0; s3 < STEPS; s3 += 3) {
    #pragma unroll
    for (int p = 0; p < 3; ++p) {
      const int s = s3 + p;
      const int z = z0 - 1 + s;
      const int zo = z - 2;
      const bool emit = (s >= 3);     // s <= 14 == CZ+2 always
      const int NEW = p, OLD = (p + 1) % 3, MID = (p + 2) % 3;
      const int RS = (p + 2) % 3;     // lds slot of plane z

      // 1. weight (dummy on non-emit keeps per-wave vmcnt count uniform)
      float w0 = 0.f, w1 = 0.f, w2 = 0.f;
      if (last) {
        const F3 wv3 = *(const F3*)(emit ? (vo + (size_t)zo * HW + wrow) : (vo + wrow));
        w0 = wv3.x; w1 = wv3.y; w2 = wv3.z;
      }
      // 2. stage plane z+1 -> slot p (1-ahead, unsinkable)
      stage(z + 1, p);
      // 3. counted wait: retire stage(s-1) (slab of plane z); newest kept =
      //    [store(s-1), weight(s), stage(s)x2] = 4 (last) / 3 (non-last)
      if (last) asm volatile("s_waitcnt vmcnt(4)" ::: "memory");
      else      asm volatile("s_waitcnt vmcnt(3)" ::: "memory");
      __builtin_amdgcn_s_barrier();
      __builtin_amdgcn_sched_barrier(0);

      // 4. read plane z's 5 rows -> NEW reg set
      {
        const float* rp = &slab[RS][0][0];
        #pragma unroll
        for (int r = 0; r < 5; ++r) {
          xa[NEW][r][0] = rp[roff[r]];
          xa[NEW][r][1] = rp[roff[r] + 1];
          xa[NEW][r][2] = rp[roff[r] + 2];
        }
      }

      // 5. M(z-1): 7-pt cross min (center plane = MID)
      float xl[3], xr[3];
      #pragma unroll
      for (int r = 0; r < 3; ++r) {
        xl[r] = __shfl_up(xa[MID][r + 1][2], 1, 64);
        xr[r] = __shfl_down(xa[MID][r + 1][0], 1, 64);
        if (l0) xl[r] = FLT_MAX;
        if (l63) xr[r] = FLT_MAX;
      }
      float Mc[3][3];
      #pragma unroll
      for (int r = 0; r < 3; ++r) {
        #pragma unroll
        for (int c = 0; c < 3; ++c) {
          const float le = (c == 0) ? xl[r] : xa[MID][r + 1][c - 1];
          const float ri = (c == 2) ? xr[r] : xa[MID][r + 1][c + 1];
          float v = min3f(xa[MID][r + 1][c], le, ri);
          v = min3f(v, xa[MID][r][c], xa[MID][r + 2][c]);       // y+-1
          v = min3f(v, xa[OLD][r + 1][c], xa[NEW][r + 1][c]);   // z+-1
          Mc[r][c] = v;
        }
      }
      if (ytop) { Mc[0][0] = Mc[0][1] = Mc[0][2] = -FLT_MAX; }
      if (ybot) { Mc[2][0] = Mc[2][1] = Mc[2][2] = -FLT_MAX; }

      // 6. hxy(z-1): separable 3x3 max
      float rm[3];
      #pragma unroll
      for (int c = 0; c < 3; ++c) rm[c] = max3f(Mc[0][c], Mc[1][c], Mc[2][c]);
      float ml = __shfl_up(rm[2], 1, 64);
      float mr = __shfl_down(rm[0], 1, 64);
      if (l0) ml = -FLT_MAX;
      if (l63) mr = -FLT_MAX;
      float h0c[3];
      h0c[0] = max3f(ml, rm[0], rm[1]);
      h0c[1] = max3f(rm[0], rm[1], rm[2]);
      h0c[2] = max3f(rm[1], rm[2], mr);

      // 7. out(z-2) = relu(x - relu(P - M)); uniform 1 store/step
      {
        const bool zlo = (zo > 0), zhi = (zo < D - 1);
        float o[3];
        #pragma unroll
        for (int c = 0; c < 3; ++c) {
          float P = h1[c];
          if (zlo) P = fmaxf(P, h2[c]);
          if (zhi) P = fmaxf(P, h0c[c]);
          const float contour = fmaxf(P - Mprev[c], 0.0f);
          o[c] = fmaxf(xa[OLD][2][c] - contour, 0.0f);
        }
        float* dst = (!last && emit) ? (vd + (size_t)zo * HW + wrow) : dmp;
        *(F3*)dst = {o[0], o[1], o[2]};
        if (last && emit) {
          sp += o[0] * w0 + o[1] * w1 + o[2] * w2;
          ss += o[0] + o[1] + o[2];
        }
      }
      #pragma unroll
      for (int c = 0; c < 3; ++c) {
        h2[c] = h1[c]; h1[c] = h0c[c]; Mprev[c] = Mc[1][c];
      }
    }
  }

  if (last) {
    #pragma unroll
    for (int off = 32; off > 0; off >>= 1) {
      sp += __shfl_down(sp, off, 64);
      ss += __shfl_down(ss, off, 64);
    }
    if (lane == 0) {
      const int lin = (b * NCH + chunk) * H + gy;
      part[2 * lin] = (double)sp;
      part[2 * lin + 1] = (double)ss;
    }
  }
}

__global__ void finalize_kernel(const double* __restrict__ pa,
                                const double* __restrict__ pb,
                                float* __restrict__ out, int npart) {
  __shared__ double red[4][4];
  double s[4] = {0, 0, 0, 0};
  for (int i = threadIdx.x; i < npart; i += 256) {
    s[0] += pa[2 * i];
    s[1] += pa[2 * i + 1];
    s[2] += pb[2 * i];
    s[3] += pb[2 * i + 1];
  }
  #pragma unroll
  for (int off = 32; off > 0; off >>= 1)
    #pragma unroll
    for (int j = 0; j < 4; ++j) s[j] += __shfl_down(s[j], off, 64);
  const int wave = threadIdx.x >> 6, lane = threadIdx.x & 63;
  if (lane == 0)
    for (int j = 0; j < 4; ++j) red[j][wave] = s[j];
  __syncthreads();
  if (threadIdx.x == 0) {
    double t[4];
    for (int j = 0; j < 4; ++j)
      t[j] = red[j][0] + red[j][1] + red[j][2] + red[j][3];
    const double recall = (t[0] + 1e-12) / (t[1] + 1e-12);
    const double accv = (t[2] + 1e-12) / (t[3] + 1e-12);
    const double cldice = 2.0 * recall * accv / (recall + accv);
    out[0] = (float)(1.0 - cldice);
  }
}

extern "C" void kernel_launch(void* const* d_in, const int* in_sizes, int n_in,
                              void* d_out, int out_size, void* d_ws, size_t ws_size,
                              hipStream_t stream) {
  const float* pred = (const float*)d_in[0];
  const float* target = (const float*)d_in[1];
  float* out = (float*)d_out;
  const size_t NT = (size_t)VOL * B;

  const dim3 blk(256, 1, 1);
  const size_t need_merged =
      4 * NT * sizeof(float) + 4 * NPART * sizeof(double) + DUMPSZ * sizeof(float);

  if (ws_size >= need_merged) {
    float* a0 = (float*)d_ws;
    float* a1 = a0 + NT;
    float* c0 = a1 + NT;
    float* c1 = c0 + NT;
    double* pA = (double*)(c1 + NT);
    double* pB = pA + 2 * NPART;
    float* dump = (float*)(pB + 2 * NPART);
    const dim3 grd(NGY, NCH, 2 * B);   // 3072 blocks = 12/CU supplied
    skel_iter<<<grd, blk, 0, stream>>>(target, a0, pred, pA, pred, c0, target, pB, dump, 0);
    skel_iter<<<grd, blk, 0, stream>>>(a0, a1, pred, pA, c0, c1, target, pB, dump, 0);
    skel_iter<<<grd, blk, 0, stream>>>(a1, a0, pred, pA, c1, c0, target, pB, dump, 0);
    skel_iter<<<grd, blk, 0, stream>>>(a0, a1, pred, pA, c0, c1, target, pB, dump, 0);
    skel_iter<<<grd, blk, 0, stream>>>(a1, a0, pred, pA, c1, c0, target, pB, dump, 1);
    finalize_kernel<<<1, 256, 0, stream>>>(pA, pB, out, NPART);
  } else {
    float* b0 = (float*)d_ws;
    float* b1 = b0 + NT;
    double* pA = (double*)(b1 + NT);
    double* pB = pA + 2 * NPART;
    float* dump = (float*)(pB + 2 * NPART);
    const dim3 grd(NGY, NCH, B);       // chain 0 only, 1536 blocks
    skel_iter<<<grd, blk, 0, stream>>>(target, b0, pred, pA, nullptr, nullptr, nullptr, nullptr, dump, 0);
    skel_iter<<<grd, blk, 0, stream>>>(b0, b1, pred, pA, nullptr, nullptr, nullptr, nullptr, dump, 0);
    skel_iter<<<grd, blk, 0, stream>>>(b1, b0, pred, pA, nullptr, nullptr, nullptr, nullptr, dump, 0);
    skel_iter<<<grd, blk, 0, stream>>>(b0, b1, pred, pA, nullptr, nullptr, nullptr, nullptr, dump, 0);
    skel_iter<<<grd, blk, 0, stream>>>(b1, b0, pred, pA, nullptr, nullptr, nullptr, nullptr, dump, 1);
    skel_iter<<<grd, blk, 0, stream>>>(pred, b0, target, pB, nullptr, nullptr, nullptr, nullptr, dump, 0);
    skel_iter<<<grd, blk, 0, stream>>>(b0, b1, target, pB, nullptr, nullptr, nullptr, nullptr, dump, 0);
    skel_iter<<<grd, blk, 0, stream>>>(b1, b0, target, pB, nullptr, nullptr, nullptr, nullptr, dump, 0);
    skel_iter<<<grd, blk, 0, stream>>>(b0, b1, target, pB, nullptr, nullptr, nullptr, nullptr, dump, 0);
    skel_iter<<<grd, blk, 0, stream>>>(b1, b0, target, pB, nullptr, nullptr, nullptr, nullptr, dump, 1);
    finalize_kernel<<<1, 256, 0, stream>>>(pA, pB, out, NPART);
  }
}

// Round 11
// 394.273 us; speedup vs baseline: 2.1109x; 2.1109x over previous
//
#include <hip/hip_runtime.h>
#include <cfloat>

// ClDiceLoss (B=2, C=1, 192^3) fp32 — LDS-staged register-streaming skeletonize.
//
// Round-18 = round-17 with ONE change: __launch_bounds__(256,6) -> (256,4).
// r17 counters: occupancy 31->66% (ring-3 LDS ceiling + CZ=12 supply WORKED)
// but VGPR=40 + WRITE 212MB + FETCH 259MB = the (256,6) spill signature
// (3rd occurrence: rounds 5/9/10). Empirical toolchain rule: (256,6) clamps
// this kernel to 40 VGPR and spills its ~60-80 live floats (the barrier-
// pinned LDS protocol makes the xa ring genuinely live: ds_reads cannot
// sink across s_barrier memory clobbers); (256,4) yields VGPR=60, no spill
// (rounds 6/7). Runtime residency is set by ACTUAL resources (VGPR~60 -> 8
// blocks/CU, LDS 18.4KB -> 8, supply 12), not by the launch_bounds arg.
//
// Design (proven r17, absmax=0): ring-3 slab (18.4KB), CZ=12 (3072 blocks
// = 12/CU supplied), 1-ahead unsinkable staging via global_load_lds, ONE
// barrier/step, counted vmcnt retiring stage(s-1): 4 (last) / 3 (non-last),
// uniform op protocol (dummy store/weight; shared 768B dump row - races
// harmless, write-only). Slot safety: stage(s) overwrites the slot read at
// s-2; reads drained before barrier(s-1); stage(s) issues after it.
// Kept: bijective XCD swizzle, dwordx3 stores, separable 3x3 max, y/z
// boundary handling (clamp-dup min-neutral; -inf M rows; zlo/zhi guards).

constexpr int D = 192, H = 192, W = 192, B = 2;
constexpr int HW = H * W;
constexpr int VOL = D * HW;
constexpr int CZ = 12;               // z-chunk (divides D; mult of 3 for slots)
constexpr int NCH = D / CZ;          // 16
constexpr int WPB = 4;               // waves (rows) per block
constexpr int NGY = H / WPB;         // 48
constexpr int STEPS = 15;            // s=0..14; emit s in [3, CZ+2]=[3,14]
constexpr int NPART = B * NCH * H;   // 6144 per chain
constexpr int DUMPSZ = 192;          // one shared dummy row (racy, write-only)

struct F3 { float x, y, z; };

typedef __attribute__((address_space(3))) float lds_f;
typedef __attribute__((address_space(1))) const float glb_f;

__device__ __forceinline__ float min3f(float a, float b, float c) {
  return fminf(fminf(a, b), c);
}
__device__ __forceinline__ float max3f(float a, float b, float c) {
  return fmaxf(fmaxf(a, b), c);
}

__global__ __launch_bounds__(256, 4) void skel_iter(
    const float* __restrict__ srcA, float* __restrict__ dstA,
    const float* __restrict__ othA, double* __restrict__ partA,
    const float* __restrict__ srcB, float* __restrict__ dstB,
    const float* __restrict__ othB, double* __restrict__ partB,
    float* __restrict__ dump, int last) {
  __shared__ float slab[3][8][192];   // ring-3 of 8-row plane slabs (18.4 KB)

  const int tid = threadIdx.x, lane = tid & 63, wv = tid >> 6;
  const int bid0 = blockIdx.x + gridDim.x * (blockIdx.y + gridDim.y * blockIdx.z);
  const int nwg = gridDim.x * gridDim.y * gridDim.z;
  const int wid = (bid0 & 7) * (nwg >> 3) + (bid0 >> 3);   // XCD swizzle
  const int gyg = wid % NGY;
  const int combo = wid / NGY;
  const int chunk = combo % NCH;
  const int bz = combo / NCH;
  const int b = bz % B;
  const int chain = bz / B;

  const int gy0 = gyg * WPB;
  const int gy = gy0 + wv;

  const float* __restrict__ vs = (chain ? srcB : srcA) + (size_t)b * VOL;
  float* __restrict__ vd = (chain ? dstB : dstA) + (size_t)b * VOL;
  const float* __restrict__ vo = (chain ? othB : othA) + (size_t)b * VOL;
  double* __restrict__ part = chain ? partB : partA;

  const int z0 = chunk * CZ;          // z0 % 3 == 0 (CZ mult of 3)
  const int c0 = 3 * lane;
  const int wrow = gy * W + c0;
  float* __restrict__ dmp = dump + c0;   // shared dummy row; races harmless

  // slab-row read offsets (floats), y-clamped to duplicated edge rows
  int roff[5];
  #pragma unroll
  for (int r = 0; r < 5; ++r) {
    const int i = min(max(gy - 2 + r, 0), H - 1) - (gy0 - 2);
    roff[r] = i * 192 + c0;
  }
  const bool ytop = (gy == 0), ybot = (gy == H - 1);
  const bool l0 = (lane == 0), l63 = (lane == 63);

  // staging rows owned by this wave: slab rows wv and wv+4
  const int g0 = min(max(gy0 - 2 + wv, 0), H - 1);
  const int g1 = min(max(gy0 + 2 + wv, 0), H - 1);

  auto stage = [&](int plane, int slot) {
    const int zc = min(max(plane, 0), D - 1);
    const float* s0 = vs + (size_t)zc * HW + (size_t)g0 * W + c0;
    const float* s1 = vs + (size_t)zc * HW + (size_t)g1 * W + c0;
    __builtin_amdgcn_global_load_lds((glb_f*)s0, (lds_f*)&slab[slot][wv][0], 12, 0, 0);
    __builtin_amdgcn_global_load_lds((glb_f*)s1, (lds_f*)&slab[slot][wv + 4][0], 12, 0, 0);
  };

  float xa[3][5][3];                  // plane reg ring (mod-3)
  float Mprev[3] = {0, 0, 0}, h1[3] = {0, 0, 0}, h2[3] = {0, 0, 0};
  float sp = 0.0f, ss = 0.0f;

  // ---- prologue ----
  // Seed regs: OLD(=xa[1]) <- plane z0-3 rows gy-1..gy+1; MID(=xa[2]) <-
  // plane z0-2 all 5 rows. Then put plane z0-1 in slot 2 (read at s=0).
  stage(z0 - 3, 0);
  stage(z0 - 2, 1);
  asm volatile("s_waitcnt vmcnt(0)" ::: "memory");
  __builtin_amdgcn_s_barrier();
  __builtin_amdgcn_sched_barrier(0);
  {
    const float* sp0 = &slab[0][0][0];
    const float* sp1 = &slab[1][0][0];
    #pragma unroll
    for (int r = 1; r <= 3; ++r) {
      xa[1][r][0] = sp0[roff[r]]; xa[1][r][1] = sp0[roff[r] + 1]; xa[1][r][2] = sp0[roff[r] + 2];
    }
    #pragma unroll
    for (int r = 0; r < 5; ++r) {
      xa[2][r][0] = sp1[roff[r]]; xa[2][r][1] = sp1[roff[r] + 1]; xa[2][r][2] = sp1[roff[r] + 2];
    }
  }
  xa[1][0][0] = xa[1][0][1] = xa[1][0][2] = 0.0f;   // never read; keep defined
  xa[1][4][0] = xa[1][4][1] = xa[1][4][2] = 0.0f;
  stage(z0 - 1, 2);
  *(F3*)dmp = {0.0f, 0.0f, 0.0f};     // protocol store
  asm volatile("s_waitcnt lgkmcnt(0)" ::: "memory");
  __builtin_amdgcn_s_barrier();
  __builtin_amdgcn_sched_barrier(0);

  #pragma unroll 1
  for (int s3 = 0; s3 < STEPS; s3 += 3) {
    #pragma unroll
    for (int p = 0; p < 3; ++p) {
      const int s = s3 + p;
      const int z = z0 - 1 + s;
      const int zo = z - 2;
      const bool emit = (s >= 3);     // s <= 14 == CZ+2 always
      const int NEW = p, OLD = (p + 1) % 3, MID = (p + 2) % 3;
      const int RS = (p + 2) % 3;     // lds slot of plane z

      // 1. weight (dummy on non-emit keeps per-wave vmcnt count uniform)
      float w0 = 0.f, w1 = 0.f, w2 = 0.f;
      if (last) {
        const F3 wv3 = *(const F3*)(emit ? (vo + (size_t)zo * HW + wrow) : (vo + wrow));
        w0 = wv3.x; w1 = wv3.y; w2 = wv3.z;
      }
      // 2. stage plane z+1 -> slot p (1-ahead, unsinkable)
      stage(z + 1, p);
      // 3. counted wait: retire stage(s-1) (slab of plane z); newest kept =
      //    [store(s-1), weight(s), stage(s)x2] = 4 (last) / 3 (non-last)
      if (last) asm volatile("s_waitcnt vmcnt(4)" ::: "memory");
      else      asm volatile("s_waitcnt vmcnt(3)" ::: "memory");
      __builtin_amdgcn_s_barrier();
      __builtin_amdgcn_sched_barrier(0);

      // 4. read plane z's 5 rows -> NEW reg set
      {
        const float* rp = &slab[RS][0][0];
        #pragma unroll
        for (int r = 0; r < 5; ++r) {
          xa[NEW][r][0] = rp[roff[r]];
          xa[NEW][r][1] = rp[roff[r] + 1];
          xa[NEW][r][2] = rp[roff[r] + 2];
        }
      }

      // 5. M(z-1): 7-pt cross min (center plane = MID)
      float xl[3], xr[3];
      #pragma unroll
      for (int r = 0; r < 3; ++r) {
        xl[r] = __shfl_up(xa[MID][r + 1][2], 1, 64);
        xr[r] = __shfl_down(xa[MID][r + 1][0], 1, 64);
        if (l0) xl[r] = FLT_MAX;
        if (l63) xr[r] = FLT_MAX;
      }
      float Mc[3][3];
      #pragma unroll
      for (int r = 0; r < 3; ++r) {
        #pragma unroll
        for (int c = 0; c < 3; ++c) {
          const float le = (c == 0) ? xl[r] : xa[MID][r + 1][c - 1];
          const float ri = (c == 2) ? xr[r] : xa[MID][r + 1][c + 1];
          float v = min3f(xa[MID][r + 1][c], le, ri);
          v = min3f(v, xa[MID][r][c], xa[MID][r + 2][c]);       // y+-1
          v = min3f(v, xa[OLD][r + 1][c], xa[NEW][r + 1][c]);   // z+-1
          Mc[r][c] = v;
        }
      }
      if (ytop) { Mc[0][0] = Mc[0][1] = Mc[0][2] = -FLT_MAX; }
      if (ybot) { Mc[2][0] = Mc[2][1] = Mc[2][2] = -FLT_MAX; }

      // 6. hxy(z-1): separable 3x3 max
      float rm[3];
      #pragma unroll
      for (int c = 0; c < 3; ++c) rm[c] = max3f(Mc[0][c], Mc[1][c], Mc[2][c]);
      float ml = __shfl_up(rm[2], 1, 64);
      float mr = __shfl_down(rm[0], 1, 64);
      if (l0) ml = -FLT_MAX;
      if (l63) mr = -FLT_MAX;
      float h0c[3];
      h0c[0] = max3f(ml, rm[0], rm[1]);
      h0c[1] = max3f(rm[0], rm[1], rm[2]);
      h0c[2] = max3f(rm[1], rm[2], mr);

      // 7. out(z-2) = relu(x - relu(P - M)); uniform 1 store/step
      {
        const bool zlo = (zo > 0), zhi = (zo < D - 1);
        float o[3];
        #pragma unroll
        for (int c = 0; c < 3; ++c) {
          float P = h1[c];
          if (zlo) P = fmaxf(P, h2[c]);
          if (zhi) P = fmaxf(P, h0c[c]);
          const float contour = fmaxf(P - Mprev[c], 0.0f);
          o[c] = fmaxf(xa[OLD][2][c] - contour, 0.0f);
        }
        float* dst = (!last && emit) ? (vd + (size_t)zo * HW + wrow) : dmp;
        *(F3*)dst = {o[0], o[1], o[2]};
        if (last && emit) {
          sp += o[0] * w0 + o[1] * w1 + o[2] * w2;
          ss += o[0] + o[1] + o[2];
        }
      }
      #pragma unroll
      for (int c = 0; c < 3; ++c) {
        h2[c] = h1[c]; h1[c] = h0c[c]; Mprev[c] = Mc[1][c];
      }
    }
  }

  if (last) {
    #pragma unroll
    for (int off = 32; off > 0; off >>= 1) {
      sp += __shfl_down(sp, off, 64);
      ss += __shfl_down(ss, off, 64);
    }
    if (lane == 0) {
      const int lin = (b * NCH + chunk) * H + gy;
      part[2 * lin] = (double)sp;
      part[2 * lin + 1] = (double)ss;
    }
  }
}

__global__ void finalize_kernel(const double* __restrict__ pa,
                                const double* __restrict__ pb,
                                float* __restrict__ out, int npart) {
  __shared__ double red[4][4];
  double s[4] = {0, 0, 0, 0};
  for (int i = threadIdx.x; i < npart; i += 256) {
    s[0] += pa[2 * i];
    s[1] += pa[2 * i + 1];
    s[2] += pb[2 * i];
    s[3] += pb[2 * i + 1];
  }
  #pragma unroll
  for (int off = 32; off > 0; off >>= 1)
    #pragma unroll
    for (int j = 0; j < 4; ++j) s[j] += __shfl_down(s[j], off, 64);
  const int wave = threadIdx.x >> 6, lane = threadIdx.x & 63;
  if (lane == 0)
    for (int j = 0; j < 4; ++j) red[j][wave] = s[j];
  __syncthreads();
  if (threadIdx.x == 0) {
    double t[4];
    for (int j = 0; j < 4; ++j)
      t[j] = red[j][0] + red[j][1] + red[j][2] + red[j][3];
    const double recall = (t[0] + 1e-12) / (t[1] + 1e-12);
    const double accv = (t[2] + 1e-12) / (t[3] + 1e-12);
    const double cldice = 2.0 * recall * accv / (recall + accv);
    out[0] = (float)(1.0 - cldice);
  }
}

extern "C" void kernel_launch(void* const* d_in, const int* in_sizes, int n_in,
                              void* d_out, int out_size, void* d_ws, size_t ws_size,
                              hipStream_t stream) {
  const float* pred = (const float*)d_in[0];
  const float* target = (const float*)d_in[1];
  float* out = (float*)d_out;
  const size_t NT = (size_t)VOL * B;

  const dim3 blk(256, 1, 1);
  const size_t need_merged =
      4 * NT * sizeof(float) + 4 * NPART * sizeof(double) + DUMPSZ * sizeof(float);

  if (ws_size >= need_merged) {
    float* a0 = (float*)d_ws;
    float* a1 = a0 + NT;
    float* c0 = a1 + NT;
    float* c1 = c0 + NT;
    double* pA = (double*)(c1 + NT);
    double* pB = pA + 2 * NPART;
    float* dump = (float*)(pB + 2 * NPART);
    const dim3 grd(NGY, NCH, 2 * B);   // 3072 blocks = 12/CU supplied
    skel_iter<<<grd, blk, 0, stream>>>(target, a0, pred, pA, pred, c0, target, pB, dump, 0);
    skel_iter<<<grd, blk, 0, stream>>>(a0, a1, pred, pA, c0, c1, target, pB, dump, 0);
    skel_iter<<<grd, blk, 0, stream>>>(a1, a0, pred, pA, c1, c0, target, pB, dump, 0);
    skel_iter<<<grd, blk, 0, stream>>>(a0, a1, pred, pA, c0, c1, target, pB, dump, 0);
    skel_iter<<<grd, blk, 0, stream>>>(a1, a0, pred, pA, c1, c0, target, pB, dump, 1);
    finalize_kernel<<<1, 256, 0, stream>>>(pA, pB, out, NPART);
  } else {
    float* b0 = (float*)d_ws;
    float* b1 = b0 + NT;
    double* pA = (double*)(b1 + NT);
    double* pB = pA + 2 * NPART;
    float* dump = (float*)(pB + 2 * NPART);
    const dim3 grd(NGY, NCH, B);       // chain 0 only, 1536 blocks
    skel_iter<<<grd, blk, 0, stream>>>(target, b0, pred, pA, nullptr, nullptr, nullptr, nullptr, dump, 0);
    skel_iter<<<grd, blk, 0, stream>>>(b0, b1, pred, pA, nullptr, nullptr, nullptr, nullptr, dump, 0);
    skel_iter<<<grd, blk, 0, stream>>>(b1, b0, pred, pA, nullptr, nullptr, nullptr, nullptr, dump, 0);
    skel_iter<<<grd, blk, 0, stream>>>(b0, b1, pred, pA, nullptr, nullptr, nullptr, nullptr, dump, 0);
    skel_iter<<<grd, blk, 0, stream>>>(b1, b0, pred, pA, nullptr, nullptr, nullptr, nullptr, dump, 1);
    skel_iter<<<grd, blk, 0, stream>>>(pred, b0, target, pB, nullptr, nullptr, nullptr, nullptr, dump, 0);
    skel_iter<<<grd, blk, 0, stream>>>(b0, b1, target, pB, nullptr, nullptr, nullptr, nullptr, dump, 0);
    skel_iter<<<grd, blk, 0, stream>>>(b1, b0, target, pB, nullptr, nullptr, nullptr, nullptr, dump, 0);
    skel_iter<<<grd, blk, 0, stream>>>(b0, b1, target, pB, nullptr, nullptr, nullptr, nullptr, dump, 0);
    skel_iter<<<grd, blk, 0, stream>>>(b1, b0, target, pB, nullptr, nullptr, nullptr, nullptr, dump, 1);
    finalize_kernel<<<1, 256, 0, stream>>>(pA, pB, out, NPART);
  }
}

// Round 12
// 392.614 us; speedup vs baseline: 2.1198x; 1.0042x over previous
//
#include <hip/hip_runtime.h>
#include <cfloat>

// ClDiceLoss (B=2, C=1, 192^3) fp32 — LDS-staged register-streaming skeletonize.
//
// Round-19 = round-18 + RACE FIX + b96 LDS reads.
// r18 (ring-3, 1 barrier/step, no spill) hit absmax=0.0039: rows 0/4 of the
// per-step ds_read are first CONSUMED at step s+1, so a wave can pass
// barrier(s+1) with those reads pending; stage(s+2) (issued before
// barrier(s+2)) overwrites that slot -> halo rows read plane z+3. r17's
// spill / r7's ring-4 masked it. FIX: merge lgkmcnt(0) into the counted
// wait before every barrier -> all slot reads retired at barrier arrival;
// stage(s+2) (after barrier(s+1)) can never clobber a pending read.
// Also: 15 scalar LDS reads/step -> 5 ds_read_b96 (F3 reads, 4B-aligned).
//
// Carried: ring-3 slab 18.4KB, CZ=12 (3072 blocks), 1-ahead unsinkable
// global_load_lds staging, counted vmcnt (4 last / 3 non-last) retiring
// stage(s-1), uniform op protocol (dummy store/weight), launch_bounds
// (256,4) (VGPR=60, no spill — (256,6) clamps to 40 and spills: r5/r9/r10),
// bijective XCD swizzle, dwordx3 stores, separable 3x3 max, y/z boundary
// handling (clamp-dup min-neutral; -inf M rows; zlo/zhi guards).

constexpr int D = 192, H = 192, W = 192, B = 2;
constexpr int HW = H * W;
constexpr int VOL = D * HW;
constexpr int CZ = 12;               // z-chunk (divides D; mult of 3 for slots)
constexpr int NCH = D / CZ;          // 16
constexpr int WPB = 4;               // waves (rows) per block
constexpr int NGY = H / WPB;         // 48
constexpr int STEPS = 15;            // s=0..14; emit s in [3, CZ+2]=[3,14]
constexpr int NPART = B * NCH * H;   // 6144 per chain
constexpr int DUMPSZ = 192;          // one shared dummy row (racy, write-only)

struct F3 { float x, y, z; };

typedef __attribute__((address_space(3))) float lds_f;
typedef __attribute__((address_space(1))) const float glb_f;

__device__ __forceinline__ float min3f(float a, float b, float c) {
  return fminf(fminf(a, b), c);
}
__device__ __forceinline__ float max3f(float a, float b, float c) {
  return fmaxf(fmaxf(a, b), c);
}

__global__ __launch_bounds__(256, 4) void skel_iter(
    const float* __restrict__ srcA, float* __restrict__ dstA,
    const float* __restrict__ othA, double* __restrict__ partA,
    const float* __restrict__ srcB, float* __restrict__ dstB,
    const float* __restrict__ othB, double* __restrict__ partB,
    float* __restrict__ dump, int last) {
  __shared__ float slab[3][8][192];   // ring-3 of 8-row plane slabs (18.4 KB)

  const int tid = threadIdx.x, lane = tid & 63, wv = tid >> 6;
  const int bid0 = blockIdx.x + gridDim.x * (blockIdx.y + gridDim.y * blockIdx.z);
  const int nwg = gridDim.x * gridDim.y * gridDim.z;
  const int wid = (bid0 & 7) * (nwg >> 3) + (bid0 >> 3);   // XCD swizzle
  const int gyg = wid % NGY;
  const int combo = wid / NGY;
  const int chunk = combo % NCH;
  const int bz = combo / NCH;
  const int b = bz % B;
  const int chain = bz / B;

  const int gy0 = gyg * WPB;
  const int gy = gy0 + wv;

  const float* __restrict__ vs = (chain ? srcB : srcA) + (size_t)b * VOL;
  float* __restrict__ vd = (chain ? dstB : dstA) + (size_t)b * VOL;
  const float* __restrict__ vo = (chain ? othB : othA) + (size_t)b * VOL;
  double* __restrict__ part = chain ? partB : partA;

  const int z0 = chunk * CZ;          // z0 % 3 == 0 (CZ mult of 3)
  const int c0 = 3 * lane;
  const int wrow = gy * W + c0;
  float* __restrict__ dmp = dump + c0;   // shared dummy row; races harmless

  // slab-row read offsets (floats), y-clamped to duplicated edge rows
  int roff[5];
  #pragma unroll
  for (int r = 0; r < 5; ++r) {
    const int i = min(max(gy - 2 + r, 0), H - 1) - (gy0 - 2);
    roff[r] = i * 192 + c0;
  }
  const bool ytop = (gy == 0), ybot = (gy == H - 1);
  const bool l0 = (lane == 0), l63 = (lane == 63);

  // staging rows owned by this wave: slab rows wv and wv+4
  const int g0 = min(max(gy0 - 2 + wv, 0), H - 1);
  const int g1 = min(max(gy0 + 2 + wv, 0), H - 1);

  auto stage = [&](int plane, int slot) {
    const int zc = min(max(plane, 0), D - 1);
    const float* s0 = vs + (size_t)zc * HW + (size_t)g0 * W + c0;
    const float* s1 = vs + (size_t)zc * HW + (size_t)g1 * W + c0;
    __builtin_amdgcn_global_load_lds((glb_f*)s0, (lds_f*)&slab[slot][wv][0], 12, 0, 0);
    __builtin_amdgcn_global_load_lds((glb_f*)s1, (lds_f*)&slab[slot][wv + 4][0], 12, 0, 0);
  };

  float xa[3][5][3];                  // plane reg ring (mod-3)
  float Mprev[3] = {0, 0, 0}, h1[3] = {0, 0, 0}, h2[3] = {0, 0, 0};
  float sp = 0.0f, ss = 0.0f;

  // ---- prologue ----
  // Seed regs: OLD(=xa[1]) <- plane z0-3 rows gy-1..gy+1; MID(=xa[2]) <-
  // plane z0-2 all 5 rows. Then put plane z0-1 in slot 2 (read at s=0).
  stage(z0 - 3, 0);
  stage(z0 - 2, 1);
  asm volatile("s_waitcnt vmcnt(0)" ::: "memory");
  __builtin_amdgcn_s_barrier();
  __builtin_amdgcn_sched_barrier(0);
  {
    const float* sp0 = &slab[0][0][0];
    const float* sp1 = &slab[1][0][0];
    #pragma unroll
    for (int r = 1; r <= 3; ++r) {
      const F3 v = *(const F3*)(sp0 + roff[r]);
      xa[1][r][0] = v.x; xa[1][r][1] = v.y; xa[1][r][2] = v.z;
    }
    #pragma unroll
    for (int r = 0; r < 5; ++r) {
      const F3 v = *(const F3*)(sp1 + roff[r]);
      xa[2][r][0] = v.x; xa[2][r][1] = v.y; xa[2][r][2] = v.z;
    }
  }
  xa[1][0][0] = xa[1][0][1] = xa[1][0][2] = 0.0f;   // never read; keep defined
  xa[1][4][0] = xa[1][4][1] = xa[1][4][2] = 0.0f;
  stage(z0 - 1, 2);
  *(F3*)dmp = {0.0f, 0.0f, 0.0f};     // protocol store
  asm volatile("s_waitcnt lgkmcnt(0)" ::: "memory");
  __builtin_amdgcn_s_barrier();
  __builtin_amdgcn_sched_barrier(0);

  #pragma unroll 1
  for (int s3 = 0; s3 < STEPS; s3 += 3) {
    #pragma unroll
    for (int p = 0; p < 3; ++p) {
      const int s = s3 + p;
      const int z = z0 - 1 + s;
      const int zo = z - 2;
      const bool emit = (s >= 3);     // s <= 14 == CZ+2 always
      const int NEW = p, OLD = (p + 1) % 3, MID = (p + 2) % 3;
      const int RS = (p + 2) % 3;     // lds slot of plane z

      // 1. weight (dummy on non-emit keeps per-wave vmcnt count uniform)
      float w0 = 0.f, w1 = 0.f, w2 = 0.f;
      if (last) {
        const F3 wv3 = *(const F3*)(emit ? (vo + (size_t)zo * HW + wrow) : (vo + wrow));
        w0 = wv3.x; w1 = wv3.y; w2 = wv3.z;
      }
      // 2. stage plane z+1 -> slot p (1-ahead, unsinkable)
      stage(z + 1, p);
      // 3. counted wait + RACE FIX: lgkmcnt(0) drains this wave's previous-
      //    step ds_reads (rows 0/4 are consumed a step late) so every wave
      //    reaches the barrier with its slot reads retired; stage(s+2) -
      //    issued after barrier(s+1) - can then never clobber a pending
      //    read. vmcnt retires stage(s-1): newest kept = [store(s-1),
      //    weight(s), stage(s)x2] = 4 (last) / 3 (non-last).
      if (last) asm volatile("s_waitcnt vmcnt(4) lgkmcnt(0)" ::: "memory");
      else      asm volatile("s_waitcnt vmcnt(3) lgkmcnt(0)" ::: "memory");
      __builtin_amdgcn_s_barrier();
      __builtin_amdgcn_sched_barrier(0);

      // 4. read plane z's 5 rows -> NEW reg set (ds_read_b96 each)
      {
        const float* rp = &slab[RS][0][0];
        #pragma unroll
        for (int r = 0; r < 5; ++r) {
          const F3 v = *(const F3*)(rp + roff[r]);
          xa[NEW][r][0] = v.x; xa[NEW][r][1] = v.y; xa[NEW][r][2] = v.z;
        }
      }

      // 5. M(z-1): 7-pt cross min (center plane = MID)
      float xl[3], xr[3];
      #pragma unroll
      for (int r = 0; r < 3; ++r) {
        xl[r] = __shfl_up(xa[MID][r + 1][2], 1, 64);
        xr[r] = __shfl_down(xa[MID][r + 1][0], 1, 64);
        if (l0) xl[r] = FLT_MAX;
        if (l63) xr[r] = FLT_MAX;
      }
      float Mc[3][3];
      #pragma unroll
      for (int r = 0; r < 3; ++r) {
        #pragma unroll
        for (int c = 0; c < 3; ++c) {
          const float le = (c == 0) ? xl[r] : xa[MID][r + 1][c - 1];
          const float ri = (c == 2) ? xr[r] : xa[MID][r + 1][c + 1];
          float v = min3f(xa[MID][r + 1][c], le, ri);
          v = min3f(v, xa[MID][r][c], xa[MID][r + 2][c]);       // y+-1
          v = min3f(v, xa[OLD][r + 1][c], xa[NEW][r + 1][c]);   // z+-1
          Mc[r][c] = v;
        }
      }
      if (ytop) { Mc[0][0] = Mc[0][1] = Mc[0][2] = -FLT_MAX; }
      if (ybot) { Mc[2][0] = Mc[2][1] = Mc[2][2] = -FLT_MAX; }

      // 6. hxy(z-1): separable 3x3 max
      float rm[3];
      #pragma unroll
      for (int c = 0; c < 3; ++c) rm[c] = max3f(Mc[0][c], Mc[1][c], Mc[2][c]);
      float ml = __shfl_up(rm[2], 1, 64);
      float mr = __shfl_down(rm[0], 1, 64);
      if (l0) ml = -FLT_MAX;
      if (l63) mr = -FLT_MAX;
      float h0c[3];
      h0c[0] = max3f(ml, rm[0], rm[1]);
      h0c[1] = max3f(rm[0], rm[1], rm[2]);
      h0c[2] = max3f(rm[1], rm[2], mr);

      // 7. out(z-2) = relu(x - relu(P - M)); uniform 1 store/step
      {
        const bool zlo = (zo > 0), zhi = (zo < D - 1);
        float o[3];
        #pragma unroll
        for (int c = 0; c < 3; ++c) {
          float P = h1[c];
          if (zlo) P = fmaxf(P, h2[c]);
          if (zhi) P = fmaxf(P, h0c[c]);
          const float contour = fmaxf(P - Mprev[c], 0.0f);
          o[c] = fmaxf(xa[OLD][2][c] - contour, 0.0f);
        }
        float* dst = (!last && emit) ? (vd + (size_t)zo * HW + wrow) : dmp;
        *(F3*)dst = {o[0], o[1], o[2]};
        if (last && emit) {
          sp += o[0] * w0 + o[1] * w1 + o[2] * w2;
          ss += o[0] + o[1] + o[2];
        }
      }
      #pragma unroll
      for (int c = 0; c < 3; ++c) {
        h2[c] = h1[c]; h1[c] = h0c[c]; Mprev[c] = Mc[1][c];
      }
    }
  }

  if (last) {
    #pragma unroll
    for (int off = 32; off > 0; off >>= 1) {
      sp += __shfl_down(sp, off, 64);
      ss += __shfl_down(ss, off, 64);
    }
    if (lane == 0) {
      const int lin = (b * NCH + chunk) * H + gy;
      part[2 * lin] = (double)sp;
      part[2 * lin + 1] = (double)ss;
    }
  }
}

__global__ void finalize_kernel(const double* __restrict__ pa,
                                const double* __restrict__ pb,
                                float* __restrict__ out, int npart) {
  __shared__ double red[4][4];
  double s[4] = {0, 0, 0, 0};
  for (int i = threadIdx.x; i < npart; i += 256) {
    s[0] += pa[2 * i];
    s[1] += pa[2 * i + 1];
    s[2] += pb[2 * i];
    s[3] += pb[2 * i + 1];
  }
  #pragma unroll
  for (int off = 32; off > 0; off >>= 1)
    #pragma unroll
    for (int j = 0; j < 4; ++j) s[j] += __shfl_down(s[j], off, 64);
  const int wave = threadIdx.x >> 6, lane = threadIdx.x & 63;
  if (lane == 0)
    for (int j = 0; j < 4; ++j) red[j][wave] = s[j];
  __syncthreads();
  if (threadIdx.x == 0) {
    double t[4];
    for (int j = 0; j < 4; ++j)
      t[j] = red[j][0] + red[j][1] + red[j][2] + red[j][3];
    const double recall = (t[0] + 1e-12) / (t[1] + 1e-12);
    const double accv = (t[2] + 1e-12) / (t[3] + 1e-12);
    const double cldice = 2.0 * recall * accv / (recall + accv);
    out[0] = (float)(1.0 - cldice);
  }
}

extern "C" void kernel_launch(void* const* d_in, const int* in_sizes, int n_in,
                              void* d_out, int out_size, void* d_ws, size_t ws_size,
                              hipStream_t stream) {
  const float* pred = (const float*)d_in[0];
  const float* target = (const float*)d_in[1];
  float* out = (float*)d_out;
  const size_t NT = (size_t)VOL * B;

  const dim3 blk(256, 1, 1);
  const size_t need_merged =
      4 * NT * sizeof(float) + 4 * NPART * sizeof(double) + DUMPSZ * sizeof(float);

  if (ws_size >= need_merged) {
    float* a0 = (float*)d_ws;
    float* a1 = a0 + NT;
    float* c0 = a1 + NT;
    float* c1 = c0 + NT;
    double* pA = (double*)(c1 + NT);
    double* pB = pA + 2 * NPART;
    float* dump = (float*)(pB + 2 * NPART);
    const dim3 grd(NGY, NCH, 2 * B);   // 3072 blocks = 12/CU supplied
    skel_iter<<<grd, blk, 0, stream>>>(target, a0, pred, pA, pred, c0, target, pB, dump, 0);
    skel_iter<<<grd, blk, 0, stream>>>(a0, a1, pred, pA, c0, c1, target, pB, dump, 0);
    skel_iter<<<grd, blk, 0, stream>>>(a1, a0, pred, pA, c1, c0, target, pB, dump, 0);
    skel_iter<<<grd, blk, 0, stream>>>(a0, a1, pred, pA, c0, c1, target, pB, dump, 0);
    skel_iter<<<grd, blk, 0, stream>>>(a1, a0, pred, pA, c1, c0, target, pB, dump, 1);
    finalize_kernel<<<1, 256, 0, stream>>>(pA, pB, out, NPART);
  } else {
    float* b0 = (float*)d_ws;
    float* b1 = b0 + NT;
    double* pA = (double*)(b1 + NT);
    double* pB = pA + 2 * NPART;
    float* dump = (float*)(pB + 2 * NPART);
    const dim3 grd(NGY, NCH, B);       // chain 0 only, 1536 blocks
    skel_iter<<<grd, blk, 0, stream>>>(target, b0, pred, pA, nullptr, nullptr, nullptr, nullptr, dump, 0);
    skel_iter<<<grd, blk, 0, stream>>>(b0, b1, pred, pA, nullptr, nullptr, nullptr, nullptr, dump, 0);
    skel_iter<<<grd, blk, 0, stream>>>(b1, b0, pred, pA, nullptr, nullptr, nullptr, nullptr, dump, 0);
    skel_iter<<<grd, blk, 0, stream>>>(b0, b1, pred, pA, nullptr, nullptr, nullptr, nullptr, dump, 0);
    skel_iter<<<grd, blk, 0, stream>>>(b1, b0, pred, pA, nullptr, nullptr, nullptr, nullptr, dump, 1);
    skel_iter<<<grd, blk, 0, stream>>>(pred, b0, target, pB, nullptr, nullptr, nullptr, nullptr, dump, 0);
    skel_iter<<<grd, blk, 0, stream>>>(b0, b1, target, pB, nullptr, nullptr, nullptr, nullptr, dump, 0);
    skel_iter<<<grd, blk, 0, stream>>>(b1, b0, target, pB, nullptr, nullptr, nullptr, nullptr, dump, 0);
    skel_iter<<<grd, blk, 0, stream>>>(b0, b1, target, pB, nullptr, nullptr, nullptr, nullptr, dump, 0);
    skel_iter<<<grd, blk, 0, stream>>>(b1, b0, target, pB, nullptr, nullptr, nullptr, nullptr, dump, 1);
    finalize_kernel<<<1, 256, 0, stream>>>(pA, pB, out, NPART);
  }
}

// Round 13
// 377.309 us; speedup vs baseline: 2.2058x; 1.0406x over previous
//
#include <hip/hip_runtime.h>
#include <cfloat>

// ClDiceLoss (B=2, C=1, 192^3) fp32 — LDS-staged register-streaming skeletonize.
//
// Round-20: TWO OUTPUT ROWS PER WAVE. r19 was proven-correct (absmax=0,
// VGPR=60, fetch 71MB, write 110.6MB) but stall-bound: occupancy stuck at
// ~3 blocks/CU across 3 attempts to raise it, VALU 44%, per-step ~960cy of
// which ~400 is issue. This round buys ILP/work-per-wave instead of TLP:
// wave handles rows a=gy0+2wv, a+1. Wins: M-row sharing 6->4 row-computes
// per 2 outputs (-33% min-tree VALU); ds_reads 10->6, bpermutes 20->12 per
// 2 outputs; barriers+vmcnt waits per output halved; step compute ~2x ->
// 1-ahead stage latency fully covered; staging redundancy 2.0x->1.5x;
// 2 independent row-trees interleave (~2x ILP).
// Geometry: 8 rows/block (4 waves x 2), NGY=24, grid (24,16,4)=1536;
// slab [3][12][192]=27.6KB. vmcnt: 3 stage + 2 stores + 2 weights/step ->
// vmcnt(7) last / vmcnt(5) non-last (induction incl. prologue, 2 distinct
// protocol stores). Race-fix lgkmcnt(0) merged into every wait (r19).
// Carried: launch_bounds(256,4) (cap 128; (256,6) clamps->spills r5/r9/r10),
// bijective XCD swizzle, unsinkable global_load_lds staging, uniform op
// protocol, dwordx3 stores, separable 3x3 max, y/z boundary handling
// (clamp-dup min-neutral; -inf M rows; zlo/zhi guards).

constexpr int D = 192, H = 192, W = 192, B = 2;
constexpr int HW = H * W;
constexpr int VOL = D * HW;
constexpr int CZ = 12;               // z-chunk (divides D; mult of 3)
constexpr int NCH = D / CZ;          // 16
constexpr int RPB = 8;               // output rows per block (4 waves x 2)
constexpr int NGY = H / RPB;         // 24
constexpr int STEPS = 15;            // s=0..14; emit s in [3,14]
constexpr int NPART = B * NCH * NGY * 4;  // 3072 per chain
constexpr int DUMPSZ = 384;          // two shared dummy rows (write-only)

struct F3 { float x, y, z; };

typedef __attribute__((address_space(3))) float lds_f;
typedef __attribute__((address_space(1))) const float glb_f;

__device__ __forceinline__ float min3f(float a, float b, float c) {
  return fminf(fminf(a, b), c);
}
__device__ __forceinline__ float max3f(float a, float b, float c) {
  return fmaxf(fmaxf(a, b), c);
}

__global__ __launch_bounds__(256, 4) void skel_iter(
    const float* __restrict__ srcA, float* __restrict__ dstA,
    const float* __restrict__ othA, double* __restrict__ partA,
    const float* __restrict__ srcB, float* __restrict__ dstB,
    const float* __restrict__ othB, double* __restrict__ partB,
    float* __restrict__ dump, int last) {
  __shared__ float slab[3][12][192];  // ring-3 of 12-row plane slabs (27.6 KB)

  const int tid = threadIdx.x, lane = tid & 63, wv = tid >> 6;
  const int bid0 = blockIdx.x + gridDim.x * (blockIdx.y + gridDim.y * blockIdx.z);
  const int nwg = gridDim.x * gridDim.y * gridDim.z;
  const int wid = (bid0 & 7) * (nwg >> 3) + (bid0 >> 3);   // XCD swizzle
  const int gyg = wid % NGY;
  const int combo = wid / NGY;
  const int chunk = combo % NCH;
  const int bz = combo / NCH;
  const int b = bz % B;
  const int chain = bz / B;

  const int gy0 = gyg * RPB;
  const int a = gy0 + 2 * wv;         // first output row (a, a+1)

  const float* __restrict__ vs = (chain ? srcB : srcA) + (size_t)b * VOL;
  float* __restrict__ vd = (chain ? dstB : dstA) + (size_t)b * VOL;
  const float* __restrict__ vo = (chain ? othB : othA) + (size_t)b * VOL;
  double* __restrict__ part = chain ? partB : partA;

  const int z0 = chunk * CZ;          // z0 % 3 == 0
  const int c0 = 3 * lane;
  const int wrowA = a * W + c0;
  const int wrowB = wrowA + W;
  float* __restrict__ dmp = dump + c0;
  float* __restrict__ dmp2 = dump + 192 + c0;

  const bool ytop = (a == 0), ybot = (a + 1 == H - 1);
  const bool l0 = (lane == 0), l63 = (lane == 63);

  // staging: wave fills slab rows wv, wv+4, wv+8 (global clamp-dup)
  int g[3];
  #pragma unroll
  for (int j = 0; j < 3; ++j)
    g[j] = min(max(gy0 - 2 + wv + 4 * j, 0), H - 1);

  auto stage = [&](int plane, int slot) {
    const int zc = min(max(plane, 0), D - 1);
    const float* base = vs + (size_t)zc * HW;
    __builtin_amdgcn_global_load_lds((glb_f*)(base + (size_t)g[0] * W + c0),
                                     (lds_f*)&slab[slot][wv][0], 12, 0, 0);
    __builtin_amdgcn_global_load_lds((glb_f*)(base + (size_t)g[1] * W + c0),
                                     (lds_f*)&slab[slot][wv + 4][0], 12, 0, 0);
    __builtin_amdgcn_global_load_lds((glb_f*)(base + (size_t)g[2] * W + c0),
                                     (lds_f*)&slab[slot][wv + 8][0], 12, 0, 0);
  };

  // plane reg ring: 6 rows (global a-2..a+3) per plane, mod-3 slots
  float xa[3][6][3];
  float MprevA[3] = {0, 0, 0}, h1A[3] = {0, 0, 0}, h2A[3] = {0, 0, 0};
  float MprevB[3] = {0, 0, 0}, h1B[3] = {0, 0, 0}, h2B[3] = {0, 0, 0};
  float sp = 0.0f, ss = 0.0f;

  // ---- prologue ----
  stage(z0 - 3, 0);
  stage(z0 - 2, 1);
  asm volatile("s_waitcnt vmcnt(0)" ::: "memory");
  __builtin_amdgcn_s_barrier();
  __builtin_amdgcn_sched_barrier(0);
  {
    const float* s0 = &slab[0][2 * wv][0];
    const float* s1 = &slab[1][2 * wv][0];
    #pragma unroll
    for (int r = 1; r <= 4; ++r) {    // OLD: plane z0-3, rows a-1..a+2
      const F3 v = *(const F3*)(s0 + r * 192 + c0);
      xa[1][r][0] = v.x; xa[1][r][1] = v.y; xa[1][r][2] = v.z;
    }
    #pragma unroll
    for (int r = 0; r < 6; ++r) {     // MID: plane z0-2, rows a-2..a+3
      const F3 v = *(const F3*)(s1 + r * 192 + c0);
      xa[2][r][0] = v.x; xa[2][r][1] = v.y; xa[2][r][2] = v.z;
    }
  }
  xa[1][0][0] = xa[1][0][1] = xa[1][0][2] = 0.0f;   // never read
  xa[1][5][0] = xa[1][5][1] = xa[1][5][2] = 0.0f;
  stage(z0 - 1, 2);
  *(F3*)dmp = {0.0f, 0.0f, 0.0f};     // protocol stores (distinct addrs)
  *(F3*)dmp2 = {0.0f, 0.0f, 0.0f};
  asm volatile("s_waitcnt lgkmcnt(0)" ::: "memory");
  __builtin_amdgcn_s_barrier();
  __builtin_amdgcn_sched_barrier(0);

  #pragma unroll 1
  for (int s3 = 0; s3 < STEPS; s3 += 3) {
    #pragma unroll
    for (int p = 0; p < 3; ++p) {
      const int s = s3 + p;
      const int z = z0 - 1 + s;
      const int zo = z - 2;
      const bool emit = (s >= 3);
      const int NEW = p, OLD = (p + 1) % 3, MID = (p + 2) % 3;
      const int RS = (p + 2) % 3;     // lds slot of plane z

      // 1. weights (2 rows; dummy on non-emit keeps vmcnt count uniform)
      float wa0 = 0.f, wa1 = 0.f, wa2 = 0.f, wb0 = 0.f, wb1 = 0.f, wb2 = 0.f;
      if (last) {
        const float* wbase = emit ? (vo + (size_t)zo * HW) : vo;
        const F3 wa = *(const F3*)(wbase + wrowA);
        const F3 wb = *(const F3*)(wbase + wrowB);
        wa0 = wa.x; wa1 = wa.y; wa2 = wa.z;
        wb0 = wb.x; wb1 = wb.y; wb2 = wb.z;
      }
      // 2. stage plane z+1 -> slot p (3 ops, unsinkable)
      stage(z + 1, p);
      // 3. counted wait (retire stage(s-1)) + lgkmcnt(0) race fix.
      //    newer ops = store(s-1)x2 + weight(s)x2(last) + stage(s)x3.
      if (last) asm volatile("s_waitcnt vmcnt(7) lgkmcnt(0)" ::: "memory");
      else      asm volatile("s_waitcnt vmcnt(5) lgkmcnt(0)" ::: "memory");
      __builtin_amdgcn_s_barrier();
      __builtin_amdgcn_sched_barrier(0);

      // 4. read plane z's 6 rows -> NEW reg set (b96 each)
      {
        const float* rp = &slab[RS][2 * wv][0];
        #pragma unroll
        for (int r = 0; r < 6; ++r) {
          const F3 v = *(const F3*)(rp + r * 192 + c0);
          xa[NEW][r][0] = v.x; xa[NEW][r][1] = v.y; xa[NEW][r][2] = v.z;
        }
      }

      // 5. M(z-1) rows a-1..a+2 (Mc[0..3]): 7-pt cross min, center = MID
      float xl[4], xr[4];
      #pragma unroll
      for (int r = 0; r < 4; ++r) {
        xl[r] = __shfl_up(xa[MID][r + 1][2], 1, 64);
        xr[r] = __shfl_down(xa[MID][r + 1][0], 1, 64);
        if (l0) xl[r] = FLT_MAX;
        if (l63) xr[r] = FLT_MAX;
      }
      float Mc[4][3];
      #pragma unroll
      for (int r = 0; r < 4; ++r) {
        #pragma unroll
        for (int c = 0; c < 3; ++c) {
          const float le = (c == 0) ? xl[r] : xa[MID][r + 1][c - 1];
          const float ri = (c == 2) ? xr[r] : xa[MID][r + 1][c + 1];
          float v = min3f(xa[MID][r + 1][c], le, ri);
          v = min3f(v, xa[MID][r][c], xa[MID][r + 2][c]);       // y+-1
          v = min3f(v, xa[OLD][r + 1][c], xa[NEW][r + 1][c]);   // z+-1
          Mc[r][c] = v;
        }
      }
      if (ytop) { Mc[0][0] = Mc[0][1] = Mc[0][2] = -FLT_MAX; }  // row -1
      if (ybot) { Mc[3][0] = Mc[3][1] = Mc[3][2] = -FLT_MAX; }  // row 192

      // 6. hxy(z-1) for both rows: shared vertical maxes, 4 shfl
      float vmA[3], vmB[3];
      #pragma unroll
      for (int c = 0; c < 3; ++c) {
        vmA[c] = max3f(Mc[0][c], Mc[1][c], Mc[2][c]);
        vmB[c] = max3f(Mc[1][c], Mc[2][c], Mc[3][c]);
      }
      float mlA = __shfl_up(vmA[2], 1, 64), mrA = __shfl_down(vmA[0], 1, 64);
      float mlB = __shfl_up(vmB[2], 1, 64), mrB = __shfl_down(vmB[0], 1, 64);
      if (l0) { mlA = -FLT_MAX; mlB = -FLT_MAX; }
      if (l63) { mrA = -FLT_MAX; mrB = -FLT_MAX; }
      float h0A[3], h0B[3];
      h0A[0] = max3f(mlA, vmA[0], vmA[1]);
      h0A[1] = max3f(vmA[0], vmA[1], vmA[2]);
      h0A[2] = max3f(vmA[1], vmA[2], mrA);
      h0B[0] = max3f(mlB, vmB[0], vmB[1]);
      h0B[1] = max3f(vmB[0], vmB[1], vmB[2]);
      h0B[2] = max3f(vmB[1], vmB[2], mrB);

      // 7. out(z-2) rows a, a+1; uniform 2 stores/step
      {
        const bool zlo = (zo > 0), zhi = (zo < D - 1);
        float oA[3], oB[3];
        #pragma unroll
        for (int c = 0; c < 3; ++c) {
          float PA = h1A[c], PB = h1B[c];
          if (zlo) { PA = fmaxf(PA, h2A[c]); PB = fmaxf(PB, h2B[c]); }
          if (zhi) { PA = fmaxf(PA, h0A[c]); PB = fmaxf(PB, h0B[c]); }
          oA[c] = fmaxf(xa[OLD][2][c] - fmaxf(PA - MprevA[c], 0.0f), 0.0f);
          oB[c] = fmaxf(xa[OLD][3][c] - fmaxf(PB - MprevB[c], 0.0f), 0.0f);
        }
        if (!last && emit) {
          *(F3*)(vd + (size_t)zo * HW + wrowA) = {oA[0], oA[1], oA[2]};
          *(F3*)(vd + (size_t)zo * HW + wrowB) = {oB[0], oB[1], oB[2]};
        } else {
          *(F3*)dmp = {oA[0], oA[1], oA[2]};
          *(F3*)dmp2 = {oB[0], oB[1], oB[2]};
        }
        if (last && emit) {
          sp += oA[0] * wa0 + oA[1] * wa1 + oA[2] * wa2
              + oB[0] * wb0 + oB[1] * wb1 + oB[2] * wb2;
          ss += oA[0] + oA[1] + oA[2] + oB[0] + oB[1] + oB[2];
        }
      }
      #pragma unroll
      for (int c = 0; c < 3; ++c) {
        h2A[c] = h1A[c]; h1A[c] = h0A[c]; MprevA[c] = Mc[1][c];
        h2B[c] = h1B[c]; h1B[c] = h0B[c]; MprevB[c] = Mc[2][c];
      }
    }
  }

  if (last) {
    #pragma unroll
    for (int off = 32; off > 0; off >>= 1) {
      sp += __shfl_down(sp, off, 64);
      ss += __shfl_down(ss, off, 64);
    }
    if (lane == 0) {
      const int lin = ((b * NCH + chunk) * NGY + gyg) * 4 + wv;
      part[2 * lin] = (double)sp;
      part[2 * lin + 1] = (double)ss;
    }
  }
}

__global__ void finalize_kernel(const double* __restrict__ pa,
                                const double* __restrict__ pb,
                                float* __restrict__ out, int npart) {
  __shared__ double red[4][4];
  double s[4] = {0, 0, 0, 0};
  for (int i = threadIdx.x; i < npart; i += 256) {
    s[0] += pa[2 * i];
    s[1] += pa[2 * i + 1];
    s[2] += pb[2 * i];
    s[3] += pb[2 * i + 1];
  }
  #pragma unroll
  for (int off = 32; off > 0; off >>= 1)
    #pragma unroll
    for (int j = 0; j < 4; ++j) s[j] += __shfl_down(s[j], off, 64);
  const int wave = threadIdx.x >> 6, lane = threadIdx.x & 63;
  if (lane == 0)
    for (int j = 0; j < 4; ++j) red[j][wave] = s[j];
  __syncthreads();
  if (threadIdx.x == 0) {
    double t[4];
    for (int j = 0; j < 4; ++j)
      t[j] = red[j][0] + red[j][1] + red[j][2] + red[j][3];
    const double recall = (t[0] + 1e-12) / (t[1] + 1e-12);
    const double accv = (t[2] + 1e-12) / (t[3] + 1e-12);
    const double cldice = 2.0 * recall * accv / (recall + accv);
    out[0] = (float)(1.0 - cldice);
  }
}

extern "C" void kernel_launch(void* const* d_in, const int* in_sizes, int n_in,
                              void* d_out, int out_size, void* d_ws, size_t ws_size,
                              hipStream_t stream) {
  const float* pred = (const float*)d_in[0];
  const float* target = (const float*)d_in[1];
  float* out = (float*)d_out;
  const size_t NT = (size_t)VOL * B;

  const dim3 blk(256, 1, 1);
  const size_t need_merged =
      4 * NT * sizeof(float) + 4 * NPART * sizeof(double) + DUMPSZ * sizeof(float);

  if (ws_size >= need_merged) {
    float* a0 = (float*)d_ws;
    float* a1 = a0 + NT;
    float* c0 = a1 + NT;
    float* c1 = c0 + NT;
    double* pA = (double*)(c1 + NT);
    double* pB = pA + 2 * NPART;
    float* dump = (float*)(pB + 2 * NPART);
    const dim3 grd(NGY, NCH, 2 * B);   // 1536 blocks
    skel_iter<<<grd, blk, 0, stream>>>(target, a0, pred, pA, pred, c0, target, pB, dump, 0);
    skel_iter<<<grd, blk, 0, stream>>>(a0, a1, pred, pA, c0, c1, target, pB, dump, 0);
    skel_iter<<<grd, blk, 0, stream>>>(a1, a0, pred, pA, c1, c0, target, pB, dump, 0);
    skel_iter<<<grd, blk, 0, stream>>>(a0, a1, pred, pA, c0, c1, target, pB, dump, 0);
    skel_iter<<<grd, blk, 0, stream>>>(a1, a0, pred, pA, c1, c0, target, pB, dump, 1);
    finalize_kernel<<<1, 256, 0, stream>>>(pA, pB, out, NPART);
  } else {
    float* b0 = (float*)d_ws;
    float* b1 = b0 + NT;
    double* pA = (double*)(b1 + NT);
    double* pB = pA + 2 * NPART;
    float* dump = (float*)(pB + 2 * NPART);
    const dim3 grd(NGY, NCH, B);       // chain 0 only, 768 blocks
    skel_iter<<<grd, blk, 0, stream>>>(target, b0, pred, pA, nullptr, nullptr, nullptr, nullptr, dump, 0);
    skel_iter<<<grd, blk, 0, stream>>>(b0, b1, pred, pA, nullptr, nullptr, nullptr, nullptr, dump, 0);
    skel_iter<<<grd, blk, 0, stream>>>(b1, b0, pred, pA, nullptr, nullptr, nullptr, nullptr, dump, 0);
    skel_iter<<<grd, blk, 0, stream>>>(b0, b1, pred, pA, nullptr, nullptr, nullptr, nullptr, dump, 0);
    skel_iter<<<grd, blk, 0, stream>>>(b1, b0, pred, pA, nullptr, nullptr, nullptr, nullptr, dump, 1);
    skel_iter<<<grd, blk, 0, stream>>>(pred, b0, target, pB, nullptr, nullptr, nullptr, nullptr, dump, 0);
    skel_iter<<<grd, blk, 0, stream>>>(b0, b1, target, pB, nullptr, nullptr, nullptr, nullptr, dump, 0);
    skel_iter<<<grd, blk, 0, stream>>>(b1, b0, target, pB, nullptr, nullptr, nullptr, nullptr, dump, 0);
    skel_iter<<<grd, blk, 0, stream>>>(b0, b1, target, pB, nullptr, nullptr, nullptr, nullptr, dump, 0);
    skel_iter<<<grd, blk, 0, stream>>>(b1, b0, target, pB, nullptr, nullptr, nullptr, nullptr, dump, 1);
    finalize_kernel<<<1, 256, 0, stream>>>(pA, pB, out, NPART);
  }
}